// Round 8
// baseline (225.753 us; speedup 1.0000x reference)
//
#include <hip/hip_runtime.h>
#include <cstdint>
#include <cstddef>

// ---------------------------------------------------------------------------
// QuaternionPhasorBlock.
// KV GEMM: 256x256 BK=64, A read as fp32 from x (reg-staged cvt->ds_write,
// kills the x-cast kernel), B via global_load_lds, counted vmcnt ledger,
// single barrier/tile. OUT GEMM: 256x256, grid 256 (1 round), both operands
// gload_lds, resid from fp32 x. Elementwise on fp16 KV.
// ---------------------------------------------------------------------------

typedef float    f32x4 __attribute__((ext_vector_type(4)));
typedef _Float16 f16x8 __attribute__((ext_vector_type(8)));
typedef _Float16 f16x4 __attribute__((ext_vector_type(4)));

#define DEV static __device__ __forceinline__

constexpr int BATCH = 4;
constexpr int LSEQ  = 4096;
constexpr int DIMN  = 1024;
constexpr int MROW  = BATCH * LSEQ;   // 16384
constexpr int SEG   = 128;
constexpr int SL    = LSEQ / SEG;     // 32
constexpr int NT    = DIMN / 64;      // 16 K-tiles of BK=64

DEV f32x4 qmul(f32x4 a, f32x4 b) {
  f32x4 r;
  r.x = a.x*b.x - a.y*b.y - a.z*b.z - a.w*b.w;
  r.y = a.x*b.y + a.y*b.x + a.z*b.w - a.w*b.z;
  r.z = a.x*b.z - a.y*b.w + a.z*b.x + a.w*b.y;
  r.w = a.x*b.w + a.y*b.z - a.z*b.y + a.w*b.x;
  return r;
}

DEV f32x4 h2f(f16x4 h) {
  return (f32x4){(float)h.x, (float)h.y, (float)h.z, (float)h.w};
}

DEV f16x8 cvt8(f32x4 lo, f32x4 hi) {
  f16x8 r;
  r[0] = (_Float16)lo.x; r[1] = (_Float16)lo.y; r[2] = (_Float16)lo.z; r[3] = (_Float16)lo.w;
  r[4] = (_Float16)hi.x; r[5] = (_Float16)hi.y; r[6] = (_Float16)hi.z; r[7] = (_Float16)hi.w;
  return r;
}

// ---------------- fp32 -> fp16 cast of Wk,Wv,Wo (contiguous out) -----------
__global__ __launch_bounds__(256) void k_cast_w(
    const float* __restrict__ w0, const float* __restrict__ w1,
    const float* __restrict__ w2, _Float16* __restrict__ out) {
  const int WN4 = DIMN * DIMN / 4;
  int i = blockIdx.x * 256 + threadIdx.x;
  if (i >= 3 * WN4) return;
  const float* src; int j;
  if (i < WN4)          { src = w0; j = i; }
  else if (i < 2 * WN4) { src = w1; j = i - WN4; }
  else                  { src = w2; j = i - 2 * WN4; }
  f32x4 v = ((const f32x4*)src)[j];
  f16x4 o = { (_Float16)v.x, (_Float16)v.y, (_Float16)v.z, (_Float16)v.w };
  ((f16x4*)out)[i] = o;
}

// ---------------- KV GEMM: [16384][2048] fp16 = x(fp32) @ (Wk||Wv)^T -------
// A (x) is fp32: reg-staged (8 f32x4 loads -> cvt -> 4 swizzled ds_write_b128).
// B fp16 via global_load_lds. Ledger per tile T:
//   loadA(T+1) [8 vm]; vmcnt(8) forces B(T); lgkm0 (publish writeA(T)); BAR;
//   read b frags; stageB(T+1) [4 vm]; {read a-pair; 16 MFMA} x4;
//   vmcnt(4) forces loadA(T+1) [leaves B(T+1)]; sched_barrier; writeA(ns).
__global__ __launch_bounds__(512, 2) void k_gemm_kv(
    const float* __restrict__ X, const _Float16* __restrict__ Bw,
    const float* __restrict__ biasA, const float* __restrict__ biasB,
    _Float16* __restrict__ C) {
  extern __shared__ char smem[];
  const int tid  = threadIdx.x;
  const int lane = tid & 63;
  const int wid  = tid >> 6;
  const int wr = wid >> 2, wc = wid & 3;

  const int nwg = gridDim.x;           // 512
  const int cpx = nwg >> 3;
  const int swz = (blockIdx.x & 7) * cpx + (blockIdx.x >> 3);
  const int bm = swz >> 3, bn = swz & 7;   // nbn = 8

  const int r8    = lane >> 3;
  const int sslot = (lane & 7) ^ r8;
  const float* aX = X + (size_t)bm * 256 * DIMN;
  const char* bT  = (const char*)(Bw + (size_t)bn * 256 * DIMN);

  auto regBase = [](int slot, int isB, int half) -> unsigned {
    return (unsigned)(((slot * 2 + isB) * 2 + half) * 16384);
  };
  auto stageB = [&](int half, int slot, int kt) {
    const char* gb = bT + (size_t)(half * 128) * 2048 + kt * 128;
    const unsigned reg = regBase(slot, 1, half);
#pragma unroll
    for (int i = 0; i < 2; ++i) {
      const int c = wid * 2 + i;
      const char* src = gb + (size_t)(c * 8 + r8) * 2048 + (sslot << 4);
      __builtin_amdgcn_global_load_lds(
          (const __attribute__((address_space(1))) void*)src,
          (__attribute__((address_space(3))) void*)(smem + reg + c * 1024), 16, 0, 0);
    }
  };
  f32x4 areg[4][2];
  auto loadA = [&](int kt) {
#pragma unroll
    for (int h = 0; h < 2; ++h)
#pragma unroll
      for (int i = 0; i < 2; ++i) {
        const size_t ad = (size_t)(h * 128 + (wid * 2 + i) * 8 + r8) * DIMN
                        + kt * 64 + sslot * 8;
        areg[h * 2 + i][0] = *(const f32x4*)(aX + ad);
        areg[h * 2 + i][1] = *(const f32x4*)(aX + ad + 4);
      }
  };
  auto writeA = [&](int slot) {
#pragma unroll
    for (int h = 0; h < 2; ++h)
#pragma unroll
      for (int i = 0; i < 2; ++i) {
        f16x8 v = cvt8(areg[h * 2 + i][0], areg[h * 2 + i][1]);
        *(f16x8*)(smem + regBase(slot, 0, h) + (wid * 2 + i) * 1024 + lane * 16) = v;
      }
  };
  auto fragA = [&](int slot, int m, int kk) -> f16x8 {
    const int half = m >> 2;
    const int row  = wr * 64 + (m & 3) * 16 + (lane & 15);
    const int sl   = (kk * 4 + (lane >> 4)) ^ (row & 7);
    return *(const f16x8*)(smem + regBase(slot, 0, half) + row * 128 + (sl << 4));
  };
  auto fragB = [&](int slot, int n, int kk) -> f16x8 {
    const int half = n >> 1;
    const int row  = wc * 32 + (n & 1) * 16 + (lane & 15);
    const int sl   = (kk * 4 + (lane >> 4)) ^ (row & 7);
    return *(const f16x8*)(smem + regBase(slot, 1, half) + row * 128 + (sl << 4));
  };

  f32x4 acc[8][4];
#pragma unroll
  for (int m = 0; m < 8; ++m)
#pragma unroll
    for (int n = 0; n < 4; ++n) acc[m][n] = (f32x4){0.f, 0.f, 0.f, 0.f};

  // prologue: A(0) regs + B(0) stage; force A regs; convert+write A(0)
  loadA(0);
  stageB(0, 0, 0); stageB(1, 0, 0);
  asm volatile("s_waitcnt vmcnt(4)" ::: "memory");   // forces the 8 A loads
  __builtin_amdgcn_sched_barrier(0);
  writeA(0);

#pragma unroll 2
  for (int T = 0; T < NT; ++T) {
    const int slot = T & 1, ns = slot ^ 1;
    const bool pf = (T + 1 < NT);
    if (pf) {
      loadA(T + 1);                                    // 8 vm (regs)
      asm volatile("s_waitcnt vmcnt(8)" ::: "memory"); // forces B(T)
    } else {
      asm volatile("s_waitcnt vmcnt(0)" ::: "memory");
    }
    asm volatile("s_waitcnt lgkmcnt(0)" ::: "memory"); // publish writeA(T)
    __builtin_amdgcn_s_barrier();

    f16x8 b[4][2], a2[2][2];
#pragma unroll
    for (int n = 0; n < 4; ++n) { b[n][0] = fragB(slot, n, 0); b[n][1] = fragB(slot, n, 1); }
    if (pf) { stageB(0, ns, T + 1); stageB(1, ns, T + 1); }   // 4 vm, post-BAR

#pragma unroll
    for (int mh = 0; mh < 4; ++mh) {
      a2[0][0] = fragA(slot, mh * 2, 0);     a2[0][1] = fragA(slot, mh * 2, 1);
      a2[1][0] = fragA(slot, mh * 2 + 1, 0); a2[1][1] = fragA(slot, mh * 2 + 1, 1);
      __builtin_amdgcn_s_setprio(1);
#pragma unroll
      for (int mm = 0; mm < 2; ++mm)
#pragma unroll
        for (int n = 0; n < 4; ++n) {
          acc[mh*2+mm][n] = __builtin_amdgcn_mfma_f32_16x16x32_f16(a2[mm][0], b[n][0], acc[mh*2+mm][n], 0, 0, 0);
          acc[mh*2+mm][n] = __builtin_amdgcn_mfma_f32_16x16x32_f16(a2[mm][1], b[n][1], acc[mh*2+mm][n], 0, 0, 0);
        }
      __builtin_amdgcn_s_setprio(0);
    }

    if (pf) {
      asm volatile("s_waitcnt vmcnt(4)" ::: "memory"); // forces loadA(T+1), leaves B(T+1)
      __builtin_amdgcn_sched_barrier(0);
      writeA(ns);                                      // lgkm, drained at next tile top
    }
  }

  const int r0 = bm * 256 + wr * 64 + ((lane >> 4) << 2);
  const int c0 = bn * 256 + wc * 32 + (lane & 15);
#pragma unroll
  for (int n = 0; n < 4; ++n) {
    const int col = c0 + (n >> 1) * 128 + (n & 1) * 16;
    const float bc = (col < DIMN) ? biasA[col] : biasB[col - DIMN];
#pragma unroll
    for (int m = 0; m < 8; ++m) {
      const int row = r0 + (m >> 2) * 128 + (m & 3) * 16;
#pragma unroll
      for (int t = 0; t < 4; ++t) {
        C[(size_t)(row + t) * 2048 + col] = (_Float16)(acc[m][n][t] + bc);
      }
    }
  }
}

// ---------------- OUT GEMM: 256x256, grid 256 (1 round) --------------------
// Both operands fp16 via global_load_lds. Per tile: vmcnt(0)+BAR (all
// outstanding loads ~1 tile old); staging issued post-BAR mid-tile.
// Epilogue: C fp32 = acc + bias + x (fp32 residual).
__global__ __launch_bounds__(512, 2) void k_gemm_out(
    const _Float16* __restrict__ A, const _Float16* __restrict__ Bw,
    const float* __restrict__ bias, const float* __restrict__ resid,
    float* __restrict__ C) {
  extern __shared__ char smem[];
  const int tid  = threadIdx.x;
  const int lane = tid & 63;
  const int wid  = tid >> 6;
  const int wr = wid >> 2, wc = wid & 3;

  const int nwg = gridDim.x;          // 256
  const int cpx = nwg >> 3;
  const int swz = (blockIdx.x & 7) * cpx + (blockIdx.x >> 3);
  const int bm = swz >> 2, bn = swz & 3;  // nbn = 4

  const int r8    = lane >> 3;
  const int sslot = (lane & 7) ^ r8;
  const char* aT = (const char*)(A  + (size_t)bm * 256 * DIMN);
  const char* bT = (const char*)(Bw + (size_t)bn * 256 * DIMN);

  auto regBase = [](int slot, int isB, int half) -> unsigned {
    return (unsigned)(((slot * 2 + isB) * 2 + half) * 16384);
  };
  auto stage = [&](int isB, int half, int slot, int kt) {
    const char* gb = (isB ? bT : aT) + (size_t)(half * 128) * 2048 + kt * 128;
    const unsigned reg = regBase(slot, isB, half);
#pragma unroll
    for (int i = 0; i < 2; ++i) {
      const int c = wid * 2 + i;
      const char* src = gb + (size_t)(c * 8 + r8) * 2048 + (sslot << 4);
      __builtin_amdgcn_global_load_lds(
          (const __attribute__((address_space(1))) void*)src,
          (__attribute__((address_space(3))) void*)(smem + reg + c * 1024), 16, 0, 0);
    }
  };
  auto fragA = [&](int slot, int m, int kk) -> f16x8 {
    const int half = m >> 2;
    const int row  = wr * 64 + (m & 3) * 16 + (lane & 15);
    const int sl   = (kk * 4 + (lane >> 4)) ^ (row & 7);
    return *(const f16x8*)(smem + regBase(slot, 0, half) + row * 128 + (sl << 4));
  };
  auto fragB = [&](int slot, int n, int kk) -> f16x8 {
    const int half = n >> 1;
    const int row  = wc * 32 + (n & 1) * 16 + (lane & 15);
    const int sl   = (kk * 4 + (lane >> 4)) ^ (row & 7);
    return *(const f16x8*)(smem + regBase(slot, 1, half) + row * 128 + (sl << 4));
  };

  f32x4 acc[8][4];
#pragma unroll
  for (int m = 0; m < 8; ++m)
#pragma unroll
    for (int n = 0; n < 4; ++n) acc[m][n] = (f32x4){0.f, 0.f, 0.f, 0.f};

  // prologue: full tile 0
  stage(0, 0, 0, 0); stage(0, 1, 0, 0); stage(1, 0, 0, 0); stage(1, 1, 0, 0);

#pragma unroll 2
  for (int T = 0; T < NT; ++T) {
    const int slot = T & 1, ns = slot ^ 1;
    const bool pf = (T + 1 < NT);
    asm volatile("s_waitcnt vmcnt(0)" ::: "memory");  // loads are ~1 tile old
    __builtin_amdgcn_s_barrier();

    f16x8 b[4][2], a2[2][2];
#pragma unroll
    for (int n = 0; n < 4; ++n) { b[n][0] = fragB(slot, n, 0); b[n][1] = fragB(slot, n, 1); }
    if (pf) {  // stage T+1, post-BAR (no WAR: ns not read until next BAR)
      stage(0, 0, ns, T + 1); stage(0, 1, ns, T + 1);
      stage(1, 0, ns, T + 1); stage(1, 1, ns, T + 1);
    }
#pragma unroll
    for (int mh = 0; mh < 4; ++mh) {
      a2[0][0] = fragA(slot, mh * 2, 0);     a2[0][1] = fragA(slot, mh * 2, 1);
      a2[1][0] = fragA(slot, mh * 2 + 1, 0); a2[1][1] = fragA(slot, mh * 2 + 1, 1);
      __builtin_amdgcn_s_setprio(1);
#pragma unroll
      for (int mm = 0; mm < 2; ++mm)
#pragma unroll
        for (int n = 0; n < 4; ++n) {
          acc[mh*2+mm][n] = __builtin_amdgcn_mfma_f32_16x16x32_f16(a2[mm][0], b[n][0], acc[mh*2+mm][n], 0, 0, 0);
          acc[mh*2+mm][n] = __builtin_amdgcn_mfma_f32_16x16x32_f16(a2[mm][1], b[n][1], acc[mh*2+mm][n], 0, 0, 0);
        }
      __builtin_amdgcn_s_setprio(0);
    }
  }

  const int r0 = bm * 256 + wr * 64 + ((lane >> 4) << 2);
  const int c0 = bn * 256 + wc * 32 + (lane & 15);
#pragma unroll
  for (int n = 0; n < 4; ++n) {
    const int col = c0 + (n >> 1) * 128 + (n & 1) * 16;
    const float bc = bias[col];
#pragma unroll
    for (int m = 0; m < 8; ++m) {
      const int row = r0 + (m >> 2) * 128 + (m & 3) * 16;
#pragma unroll
      for (int t = 0; t < 4; ++t) {
        const size_t off = (size_t)(row + t) * DIMN + col;
        C[off] = acc[m][n][t] + bc + resid[off];
      }
    }
  }
}

// ---------------- segment sums over fp16 KV (recompute normalize+bind) -----
__global__ __launch_bounds__(256) void k_segsum(const _Float16* __restrict__ KVh,
                                                float* __restrict__ segsum) {
  const int b = blockIdx.x >> 7, seg = blockIdx.x & 127, n = threadIdx.x;
  f32x4 ssum = (f32x4){0.f, 0.f, 0.f, 0.f};
  const size_t rb = (size_t)(b * LSEQ + seg * SL) * 2048 + n * 4;
  for (int l = 0; l < SL; ++l) {
    const size_t p = rb + (size_t)l * 2048;
    f32x4 kq = h2f(*(const f16x4*)(KVh + p));
    f32x4 vq = h2f(*(const f16x4*)(KVh + p + 1024));
    float nn = sqrtf(kq.x*kq.x + kq.y*kq.y + kq.z*kq.z + kq.w*kq.w);
    f32x4 kh = kq * (1.0f / fmaxf(nn, 1e-12f));
    ssum += qmul(vq, kh);
  }
  ((f32x4*)segsum)[(size_t)blockIdx.x * 256 + n] = ssum;
}

// ---------------- retrieve + LayerNorm fused (prefix computed in-block) ----
__global__ __launch_bounds__(256) void k_retrieve_ln(
    const _Float16* __restrict__ KVh, const float* __restrict__ segsum,
    const float* __restrict__ g, const float* __restrict__ bb,
    _Float16* __restrict__ out) {
  const int b = blockIdx.x >> 7, seg = blockIdx.x & 127, n = threadIdx.x;
  const int wid = n >> 6, lane = n & 63;
  __shared__ float p1[2][4], p2[2][4];

  f32x4 m0 = (f32x4){0.f, 0.f, 0.f, 0.f}, m1 = (f32x4){0.f, 0.f, 0.f, 0.f};
  {
    const f32x4* ss = (const f32x4*)segsum + (size_t)b * SEG * 256 + n;
    int s = 0;
    for (; s + 2 <= seg; s += 2) {
      m0 += ss[(size_t)s * 256];
      m1 += ss[(size_t)(s + 1) * 256];
    }
    if (s < seg) m0 += ss[(size_t)s * 256];
  }
  f32x4 mem = m0 + m1;

  const f32x4 gg  = ((const f32x4*)g)[n];
  const f32x4 bvv = ((const f32x4*)bb)[n];
  const size_t rb = (size_t)(b * LSEQ + seg * SL) * 2048 + n * 4;
  const int grow = b * LSEQ + seg * SL;

  f16x4 kq = *(const f16x4*)(KVh + rb);
  f16x4 vq = *(const f16x4*)(KVh + rb + 1024);
  for (int l = 0; l < SL; ++l) {
    f16x4 kqn, vqn;
    if (l + 1 < SL) {
      kqn = *(const f16x4*)(KVh + rb + (size_t)(l + 1) * 2048);
      vqn = *(const f16x4*)(KVh + rb + (size_t)(l + 1) * 2048 + 1024);
    }
    f32x4 kf = h2f(kq), vf = h2f(vq);
    float nn = sqrtf(kf.x*kf.x + kf.y*kf.y + kf.z*kf.z + kf.w*kf.w);
    f32x4 kh = kf * (1.0f / fmaxf(nn, 1e-12f));
    mem += qmul(vf, kh);
    f32x4 kc = (f32x4){kh.x, -kh.y, -kh.z, -kh.w};
    f32x4 r = qmul(mem, kc);
    r *= rsqrtf((float)(seg * SL + l + 1));

    float s1 = r.x + r.y + r.z + r.w;
    float s2 = r.x*r.x + r.y*r.y + r.z*r.z + r.w*r.w;
#pragma unroll
    for (int off = 32; off > 0; off >>= 1) {
      s1 += __shfl_down(s1, off, 64);
      s2 += __shfl_down(s2, off, 64);
    }
    if (lane == 0) { p1[l & 1][wid] = s1; p2[l & 1][wid] = s2; }
    __syncthreads();
    const float ts1 = p1[l & 1][0] + p1[l & 1][1] + p1[l & 1][2] + p1[l & 1][3];
    const float ts2 = p2[l & 1][0] + p2[l & 1][1] + p2[l & 1][2] + p2[l & 1][3];
    const float mu = ts1 * (1.0f / 1024.0f);
    const float var = ts2 * (1.0f / 1024.0f) - mu * mu;
    const float rstd = rsqrtf(var + 1e-5f);
    f32x4 nv = (r - mu) * rstd * gg + bvv;
    f16x4 o = { (_Float16)nv.x, (_Float16)nv.y, (_Float16)nv.z, (_Float16)nv.w };
    ((f16x4*)out)[(size_t)(grow + l) * 256 + n] = o;
    kq = kqn; vq = vqn;
  }
}

// ---------------------------------------------------------------------------
extern "C" void kernel_launch(void* const* d_in, const int* in_sizes, int n_in,
                              void* d_out, int out_size, void* d_ws, size_t ws_size,
                              hipStream_t stream) {
  const float* x    = (const float*)d_in[0];
  const float* Wk   = (const float*)d_in[1];
  const float* bk   = (const float*)d_in[2];
  const float* Wv   = (const float*)d_in[3];
  const float* bv   = (const float*)d_in[4];
  const float* ln_g = (const float*)d_in[5];
  const float* ln_b = (const float*)d_in[6];
  const float* Wo   = (const float*)d_in[7];
  const float* bo   = (const float*)d_in[8];
  float* out = (float*)d_out;

  char* ws = (char*)d_ws;
  size_t off = 0;
  auto alloc = [&](size_t bytes) -> void* {
    void* p = ws + off;
    off += (bytes + 255) & ~(size_t)255;
    return p;
  };
  _Float16* wkvb = (_Float16*)alloc((size_t)3 * DIMN * DIMN * 2);   // 6 MB (Wk||Wv||Wo)
  _Float16* KVh  = (_Float16*)alloc((size_t)MROW * 2 * DIMN * 2);   // 67 MB fp16 K|V
  float* segsum  = (float*)alloc((size_t)BATCH * SEG * DIMN * 4);   // 2 MB
  _Float16* nb   = (_Float16*)alloc((size_t)MROW * DIMN * 2);       // 33.5 MB
  _Float16* wob  = wkvb + (size_t)2 * DIMN * DIMN;
  (void)off; (void)ws_size; (void)in_sizes; (void)n_in; (void)out_size;

  hipFuncSetAttribute((const void*)k_gemm_kv,
                      hipFuncAttributeMaxDynamicSharedMemorySize, 131072);
  hipFuncSetAttribute((const void*)k_gemm_out,
                      hipFuncAttributeMaxDynamicSharedMemorySize, 131072);

  // W-only cast (x is consumed as fp32 by both GEMMs)
  k_cast_w<<<(3 * DIMN * DIMN / 4 + 255) / 256, 256, 0, stream>>>(Wk, Wv, Wo, wkvb);

  // fused K|V projection from fp32 x
  k_gemm_kv<<<(MROW / 256) * (2048 / 256), 512, 131072, stream>>>(
      x, wkvb, bk, bv, KVh);

  // segment sums (recompute bind) -> retrieve+LN (prefix in-block)
  k_segsum<<<BATCH * SEG, 256, 0, stream>>>(KVh, segsum);
  k_retrieve_ln<<<BATCH * SEG, 256, 0, stream>>>(KVh, segsum, ln_g, ln_b, nb);

  // output GEMM with fp32 residual from x, 1 round
  k_gemm_out<<<(MROW / 256) * (DIMN / 256), 512, 131072, stream>>>(
      nb, wob, bo, x, out);
}

// Round 9
// 208.352 us; speedup vs baseline: 1.0835x; 1.0835x over previous
//
#include <hip/hip_runtime.h>
#include <cstdint>
#include <cstddef>

// ---------------------------------------------------------------------------
// QuaternionPhasorBlock.
// KV GEMM: 256x256 BK=64 (R6 schedule, measured 83us): stage A-halves pre-gate
// vmcnt(4), B-halves under MFMA, 2 barriers/tile. OUT GEMM: 128x128, 64KB LDS,
// 256 thr, grid 1024 -> 2 resident blocks/CU (cross-block overlap), counted
// vmcnt(4) ledger. Elementwise on fp16 KV, fused casts, fused prefix+retrieve.
// ---------------------------------------------------------------------------

typedef float    f32x4 __attribute__((ext_vector_type(4)));
typedef _Float16 f16x8 __attribute__((ext_vector_type(8)));
typedef _Float16 f16x4 __attribute__((ext_vector_type(4)));

#define DEV static __device__ __forceinline__

constexpr int BATCH = 4;
constexpr int LSEQ  = 4096;
constexpr int DIMN  = 1024;
constexpr int MROW  = BATCH * LSEQ;   // 16384
constexpr int SEG   = 128;
constexpr int SL    = LSEQ / SEG;     // 32
constexpr int NT    = DIMN / 64;      // 16 K-tiles of BK=64

DEV f32x4 qmul(f32x4 a, f32x4 b) {
  f32x4 r;
  r.x = a.x*b.x - a.y*b.y - a.z*b.z - a.w*b.w;
  r.y = a.x*b.y + a.y*b.x + a.z*b.w - a.w*b.z;
  r.z = a.x*b.z - a.y*b.w + a.z*b.x + a.w*b.y;
  r.w = a.x*b.w + a.y*b.z - a.z*b.y + a.w*b.x;
  return r;
}

DEV f32x4 h2f(f16x4 h) {
  return (f32x4){(float)h.x, (float)h.y, (float)h.z, (float)h.w};
}

// ---------------- fused fp32 -> fp16 cast of x, Wk, Wv, Wo -----------------
__global__ __launch_bounds__(256) void k_cast_all(
    const float* __restrict__ x, const float* __restrict__ w0,
    const float* __restrict__ w1, const float* __restrict__ w2,
    _Float16* __restrict__ out) {
  const int XN4 = MROW * DIMN / 4;
  const int WN4 = DIMN * DIMN / 4;
  int i = blockIdx.x * 256 + threadIdx.x;
  if (i >= XN4 + 3 * WN4) return;
  const float* src; int j;
  if (i < XN4)                { src = x;  j = i; }
  else if (i < XN4 + WN4)     { src = w0; j = i - XN4; }
  else if (i < XN4 + 2 * WN4) { src = w1; j = i - XN4 - WN4; }
  else                        { src = w2; j = i - XN4 - 2 * WN4; }
  f32x4 v = ((const f32x4*)src)[j];
  f16x4 o = { (_Float16)v.x, (_Float16)v.y, (_Float16)v.z, (_Float16)v.w };
  ((f16x4*)out)[i] = o;
}

// ---------------- 256x256 GEMM (KV projection), fp16 out (R6 schedule) -----
__global__ __launch_bounds__(512, 2) void k_gemm256(
    const _Float16* __restrict__ A, const _Float16* __restrict__ Bw,
    const float* __restrict__ biasA, const float* __restrict__ biasB, int nsplit,
    _Float16* __restrict__ C, int ldC, int nbn) {
  extern __shared__ char smem[];
  const int tid  = threadIdx.x;
  const int lane = tid & 63;
  const int wid  = tid >> 6;
  const int wr = wid >> 2, wc = wid & 3;

  const int nwg = gridDim.x;
  const int cpx = nwg >> 3;
  const int swz = (blockIdx.x & 7) * cpx + (blockIdx.x >> 3);
  const int bm = swz / nbn, bn = swz % nbn;

  auto regBase = [](int slot, int isB, int half) -> unsigned {
    return (unsigned)(((slot * 2 + isB) * 2 + half) * 16384);
  };
  const int r8    = lane >> 3;
  const int sslot = (lane & 7) ^ r8;
  const char* aT = (const char*)(A  + (size_t)bm * 256 * DIMN);
  const char* bT = (const char*)(Bw + (size_t)bn * 256 * DIMN);

  auto stage = [&](int isB, int half, int slot, int kt) {
    const char* gb = (isB ? bT : aT) + (size_t)(half * 128) * 2048 + kt * 128;
    const unsigned reg = regBase(slot, isB, half);
#pragma unroll
    for (int i = 0; i < 2; ++i) {
      const int c = wid * 2 + i;
      const char* src = gb + (size_t)(c * 8 + r8) * 2048 + (sslot << 4);
      __builtin_amdgcn_global_load_lds(
          (const __attribute__((address_space(1))) void*)src,
          (__attribute__((address_space(3))) void*)(smem + reg + c * 1024), 16, 0, 0);
    }
  };
  auto fragA = [&](int slot, int m, int kk) -> f16x8 {
    const int half = m >> 2;
    const int row  = wr * 64 + (m & 3) * 16 + (lane & 15);
    const int sl   = (kk * 4 + (lane >> 4)) ^ (row & 7);
    return *(const f16x8*)(smem + regBase(slot, 0, half) + row * 128 + (sl << 4));
  };
  auto fragB = [&](int slot, int n, int kk) -> f16x8 {
    const int half = n >> 1;
    const int row  = wc * 32 + (n & 1) * 16 + (lane & 15);
    const int sl   = (kk * 4 + (lane >> 4)) ^ (row & 7);
    return *(const f16x8*)(smem + regBase(slot, 1, half) + row * 128 + (sl << 4));
  };

  f32x4 acc[8][4];
#pragma unroll
  for (int m = 0; m < 8; ++m)
#pragma unroll
    for (int n = 0; n < 4; ++n) acc[m][n] = (f32x4){0.f, 0.f, 0.f, 0.f};

  // prologue: stage tile 0 (A halves then B halves)
  stage(0, 0, 0, 0); stage(0, 1, 0, 0); stage(1, 0, 0, 0); stage(1, 1, 0, 0);

  f16x8 a[4][2], b[4][2];
#pragma unroll 2
  for (int T = 0; T < NT; ++T) {
    const int slot = T & 1, ns = slot ^ 1;
    const bool pf = (T + 1 < NT);
    if (pf) {  // A-halves of T+1
      stage(0, 0, ns, T + 1); stage(0, 1, ns, T + 1);
      asm volatile("s_waitcnt vmcnt(4)" ::: "memory");   // forces ALL of tile T
    } else {
      asm volatile("s_waitcnt vmcnt(0)" ::: "memory");
    }
    __builtin_amdgcn_s_barrier();

    // half 1: A rows 0..127 x all B
#pragma unroll
    for (int m = 0; m < 4; ++m) { a[m][0] = fragA(slot, m, 0); a[m][1] = fragA(slot, m, 1); }
#pragma unroll
    for (int n = 0; n < 4; ++n) { b[n][0] = fragB(slot, n, 0); b[n][1] = fragB(slot, n, 1); }
    __builtin_amdgcn_s_setprio(1);
#pragma unroll
    for (int m = 0; m < 4; ++m)
#pragma unroll
      for (int n = 0; n < 4; ++n) {
        acc[m][n] = __builtin_amdgcn_mfma_f32_16x16x32_f16(a[m][0], b[n][0], acc[m][n], 0, 0, 0);
        acc[m][n] = __builtin_amdgcn_mfma_f32_16x16x32_f16(a[m][1], b[n][1], acc[m][n], 0, 0, 0);
      }
    __builtin_amdgcn_s_setprio(0);

    if (pf) { stage(1, 0, ns, T + 1); stage(1, 1, ns, T + 1); }  // B-halves of T+1

    // half 2: A rows 128..255 x all B (B frags reused in-register)
#pragma unroll
    for (int m = 0; m < 4; ++m) { a[m][0] = fragA(slot, m + 4, 0); a[m][1] = fragA(slot, m + 4, 1); }
    __builtin_amdgcn_s_setprio(1);
#pragma unroll
    for (int m = 0; m < 4; ++m)
#pragma unroll
      for (int n = 0; n < 4; ++n) {
        acc[m + 4][n] = __builtin_amdgcn_mfma_f32_16x16x32_f16(a[m][0], b[n][0], acc[m + 4][n], 0, 0, 0);
        acc[m + 4][n] = __builtin_amdgcn_mfma_f32_16x16x32_f16(a[m][1], b[n][1], acc[m + 4][n], 0, 0, 0);
      }
    __builtin_amdgcn_s_setprio(0);
    __builtin_amdgcn_s_barrier();
  }

  const int r0 = bm * 256 + wr * 64 + ((lane >> 4) << 2);
  const int c0 = bn * 256 + wc * 32 + (lane & 15);
#pragma unroll
  for (int n = 0; n < 4; ++n) {
    const int col = c0 + (n >> 1) * 128 + (n & 1) * 16;
    const float bc = (col < nsplit) ? biasA[col] : biasB[col - nsplit];
#pragma unroll
    for (int m = 0; m < 8; ++m) {
      const int row = r0 + (m >> 2) * 128 + (m & 3) * 16;
#pragma unroll
      for (int t = 0; t < 4; ++t) {
        C[(size_t)(row + t) * ldC + col] = (_Float16)(acc[m][n][t] + bc);
      }
    }
  }
}

// ---------------- OUT GEMM: 128x128, 64KB LDS, 2 resident blocks/CU --------
// 4 waves (2x2 of 64x64). Per tile T: stage A(T+1) [4]; vmcnt(4) [forces
// A(T),B(T), leaves A(T+1)]; BAR; read frags; stage B(T+1) under MFMA;
// 32 MFMA; BAR.
__global__ __launch_bounds__(256, 2) void k_gemm_out(
    const _Float16* __restrict__ A, const _Float16* __restrict__ Bw,
    const float* __restrict__ bias, const _Float16* __restrict__ residH,
    float* __restrict__ C) {
  extern __shared__ char smem[];
  const int tid  = threadIdx.x;
  const int lane = tid & 63;
  const int wid  = tid >> 6;
  const int wr = wid >> 1, wc = wid & 1;

  const int nwg = gridDim.x;              // 1024
  const int cpx = nwg >> 3;
  const int swz = (blockIdx.x & 7) * cpx + (blockIdx.x >> 3);
  const int bm = swz >> 3, bn = swz & 7;  // nbn = 8

  const int r8    = lane >> 3;
  const int sslot = (lane & 7) ^ r8;
  const char* aT = (const char*)(A  + (size_t)bm * 128 * DIMN);
  const char* bT = (const char*)(Bw + (size_t)bn * 128 * DIMN);

  auto stage = [&](int isB, int slot, int kt) {   // 4 loads/thread
    const char* gb = (isB ? bT : aT) + kt * 128;
    char* dst = smem + slot * 32768 + isB * 16384;
#pragma unroll
    for (int i = 0; i < 4; ++i) {
      const int c = wid * 4 + i;                  // 16 chunks of 1KB
      const char* src = gb + (size_t)(c * 8 + r8) * 2048 + (sslot << 4);
      __builtin_amdgcn_global_load_lds(
          (const __attribute__((address_space(1))) void*)src,
          (__attribute__((address_space(3))) void*)(dst + c * 1024), 16, 0, 0);
    }
  };
  auto fragA = [&](int slot, int m, int kk) -> f16x8 {
    const int row = wr * 64 + m * 16 + (lane & 15);           // 0..127
    const int sl  = (kk * 4 + (lane >> 4)) ^ (row & 7);
    return *(const f16x8*)(smem + slot * 32768 + row * 128 + (sl << 4));
  };
  auto fragB = [&](int slot, int n, int kk) -> f16x8 {
    const int row = wc * 64 + n * 16 + (lane & 15);           // 0..127
    const int sl  = (kk * 4 + (lane >> 4)) ^ (row & 7);
    return *(const f16x8*)(smem + slot * 32768 + 16384 + row * 128 + (sl << 4));
  };

  f32x4 acc[4][4];
#pragma unroll
  for (int m = 0; m < 4; ++m)
#pragma unroll
    for (int n = 0; n < 4; ++n) acc[m][n] = (f32x4){0.f, 0.f, 0.f, 0.f};

  // prologue: stage A(0), B(0)
  stage(0, 0, 0); stage(1, 0, 0);

  f16x8 a[4][2], b[4][2];
#pragma unroll 2
  for (int T = 0; T < NT; ++T) {
    const int slot = T & 1, ns = slot ^ 1;
    const bool pf = (T + 1 < NT);
    if (pf) {
      stage(0, ns, T + 1);                               // A(T+1): 4 loads
      asm volatile("s_waitcnt vmcnt(4)" ::: "memory");   // forces A(T),B(T)
    } else {
      asm volatile("s_waitcnt vmcnt(0)" ::: "memory");
    }
    __builtin_amdgcn_s_barrier();
#pragma unroll
    for (int m = 0; m < 4; ++m) { a[m][0] = fragA(slot, m, 0); a[m][1] = fragA(slot, m, 1); }
#pragma unroll
    for (int n = 0; n < 4; ++n) { b[n][0] = fragB(slot, n, 0); b[n][1] = fragB(slot, n, 1); }
    if (pf) stage(1, ns, T + 1);                         // B(T+1) under MFMA
    __builtin_amdgcn_s_setprio(1);
#pragma unroll
    for (int m = 0; m < 4; ++m)
#pragma unroll
      for (int n = 0; n < 4; ++n) {
        acc[m][n] = __builtin_amdgcn_mfma_f32_16x16x32_f16(a[m][0], b[n][0], acc[m][n], 0, 0, 0);
        acc[m][n] = __builtin_amdgcn_mfma_f32_16x16x32_f16(a[m][1], b[n][1], acc[m][n], 0, 0, 0);
      }
    __builtin_amdgcn_s_setprio(0);
    __builtin_amdgcn_s_barrier();
  }

  const int r0 = bm * 128 + wr * 64 + ((lane >> 4) << 2);
  const int c0 = bn * 128 + wc * 64 + (lane & 15);
#pragma unroll
  for (int n = 0; n < 4; ++n) {
    const int col = c0 + n * 16;
    const float bc = bias[col];
#pragma unroll
    for (int m = 0; m < 4; ++m) {
      const int row = r0 + m * 16;
#pragma unroll
      for (int t = 0; t < 4; ++t) {
        const size_t off = (size_t)(row + t) * DIMN + col;
        C[off] = acc[m][n][t] + bc + (float)residH[off];
      }
    }
  }
}

// ---------------- segment sums over fp16 KV (recompute normalize+bind) -----
__global__ __launch_bounds__(256) void k_segsum(const _Float16* __restrict__ KVh,
                                                float* __restrict__ segsum) {
  const int b = blockIdx.x >> 7, seg = blockIdx.x & 127, n = threadIdx.x;
  f32x4 ssum = (f32x4){0.f, 0.f, 0.f, 0.f};
  const size_t rb = (size_t)(b * LSEQ + seg * SL) * 2048 + n * 4;
  for (int l = 0; l < SL; ++l) {
    const size_t p = rb + (size_t)l * 2048;
    f32x4 kq = h2f(*(const f16x4*)(KVh + p));
    f32x4 vq = h2f(*(const f16x4*)(KVh + p + 1024));
    float nn = sqrtf(kq.x*kq.x + kq.y*kq.y + kq.z*kq.z + kq.w*kq.w);
    f32x4 kh = kq * (1.0f / fmaxf(nn, 1e-12f));
    ssum += qmul(vq, kh);
  }
  ((f32x4*)segsum)[(size_t)blockIdx.x * 256 + n] = ssum;
}

// ---------------- retrieve + LayerNorm fused (prefix computed in-block) ----
__global__ __launch_bounds__(256) void k_retrieve_ln(
    const _Float16* __restrict__ KVh, const float* __restrict__ segsum,
    const float* __restrict__ g, const float* __restrict__ bb,
    _Float16* __restrict__ out) {
  const int b = blockIdx.x >> 7, seg = blockIdx.x & 127, n = threadIdx.x;
  const int wid = n >> 6, lane = n & 63;
  __shared__ float p1[2][4], p2[2][4];

  f32x4 m0 = (f32x4){0.f, 0.f, 0.f, 0.f}, m1 = (f32x4){0.f, 0.f, 0.f, 0.f};
  {
    const f32x4* ss = (const f32x4*)segsum + (size_t)b * SEG * 256 + n;
    int s = 0;
    for (; s + 2 <= seg; s += 2) {
      m0 += ss[(size_t)s * 256];
      m1 += ss[(size_t)(s + 1) * 256];
    }
    if (s < seg) m0 += ss[(size_t)s * 256];
  }
  f32x4 mem = m0 + m1;

  const f32x4 gg  = ((const f32x4*)g)[n];
  const f32x4 bvv = ((const f32x4*)bb)[n];
  const size_t rb = (size_t)(b * LSEQ + seg * SL) * 2048 + n * 4;
  const int grow = b * LSEQ + seg * SL;

  f16x4 kq = *(const f16x4*)(KVh + rb);
  f16x4 vq = *(const f16x4*)(KVh + rb + 1024);
  for (int l = 0; l < SL; ++l) {
    f16x4 kqn, vqn;
    if (l + 1 < SL) {
      kqn = *(const f16x4*)(KVh + rb + (size_t)(l + 1) * 2048);
      vqn = *(const f16x4*)(KVh + rb + (size_t)(l + 1) * 2048 + 1024);
    }
    f32x4 kf = h2f(kq), vf = h2f(vq);
    float nn = sqrtf(kf.x*kf.x + kf.y*kf.y + kf.z*kf.z + kf.w*kf.w);
    f32x4 kh = kf * (1.0f / fmaxf(nn, 1e-12f));
    mem += qmul(vf, kh);
    f32x4 kc = (f32x4){kh.x, -kh.y, -kh.z, -kh.w};
    f32x4 r = qmul(mem, kc);
    r *= rsqrtf((float)(seg * SL + l + 1));

    float s1 = r.x + r.y + r.z + r.w;
    float s2 = r.x*r.x + r.y*r.y + r.z*r.z + r.w*r.w;
#pragma unroll
    for (int off = 32; off > 0; off >>= 1) {
      s1 += __shfl_down(s1, off, 64);
      s2 += __shfl_down(s2, off, 64);
    }
    if (lane == 0) { p1[l & 1][wid] = s1; p2[l & 1][wid] = s2; }
    __syncthreads();
    const float ts1 = p1[l & 1][0] + p1[l & 1][1] + p1[l & 1][2] + p1[l & 1][3];
    const float ts2 = p2[l & 1][0] + p2[l & 1][1] + p2[l & 1][2] + p2[l & 1][3];
    const float mu = ts1 * (1.0f / 1024.0f);
    const float var = ts2 * (1.0f / 1024.0f) - mu * mu;
    const float rstd = rsqrtf(var + 1e-5f);
    f32x4 nv = (r - mu) * rstd * gg + bvv;
    f16x4 o = { (_Float16)nv.x, (_Float16)nv.y, (_Float16)nv.z, (_Float16)nv.w };
    ((f16x4*)out)[(size_t)(grow + l) * 256 + n] = o;
    kq = kqn; vq = vqn;
  }
}

// ---------------------------------------------------------------------------
extern "C" void kernel_launch(void* const* d_in, const int* in_sizes, int n_in,
                              void* d_out, int out_size, void* d_ws, size_t ws_size,
                              hipStream_t stream) {
  const float* x    = (const float*)d_in[0];
  const float* Wk   = (const float*)d_in[1];
  const float* bk   = (const float*)d_in[2];
  const float* Wv   = (const float*)d_in[3];
  const float* bv   = (const float*)d_in[4];
  const float* ln_g = (const float*)d_in[5];
  const float* ln_b = (const float*)d_in[6];
  const float* Wo   = (const float*)d_in[7];
  const float* bo   = (const float*)d_in[8];
  float* out = (float*)d_out;

  char* ws = (char*)d_ws;
  size_t off = 0;
  auto alloc = [&](size_t bytes) -> void* {
    void* p = ws + off;
    off += (bytes + 255) & ~(size_t)255;
    return p;
  };
  _Float16* xb   = (_Float16*)alloc((size_t)MROW * DIMN * 2);       // 33.5 MB
  _Float16* wkvb = (_Float16*)alloc((size_t)3 * DIMN * DIMN * 2);   // 6 MB (Wk||Wv||Wo)
  _Float16* KVh  = (_Float16*)alloc((size_t)MROW * 2 * DIMN * 2);   // 67 MB fp16 K|V
  float* segsum  = (float*)alloc((size_t)BATCH * SEG * DIMN * 4);   // 2 MB
  _Float16* nb   = (_Float16*)alloc((size_t)MROW * DIMN * 2);       // 33.5 MB
  _Float16* wob  = wkvb + (size_t)2 * DIMN * DIMN;
  (void)off; (void)ws_size; (void)in_sizes; (void)n_in; (void)out_size;

  hipFuncSetAttribute((const void*)k_gemm256,
                      hipFuncAttributeMaxDynamicSharedMemorySize, 131072);
  hipFuncSetAttribute((const void*)k_gemm_out,
                      hipFuncAttributeMaxDynamicSharedMemorySize, 65536);

  // fused casts: x||Wk||Wv||Wo -> xb||wkvb (contiguous)
  const int castN4 = MROW * DIMN / 4 + 3 * DIMN * DIMN / 4;
  k_cast_all<<<(castN4 + 255) / 256, 256, 0, stream>>>(x, Wk, Wv, Wo, xb);

  // fused K|V projection: [16384][2048] fp16 = xb @ (Wk||Wv)^T
  k_gemm256<<<(MROW / 256) * (2048 / 256), 512, 131072, stream>>>(
      xb, wkvb, bk, bv, 1024, KVh, 2048, 2048 / 256);

  // segment sums (recompute bind) -> retrieve+LN (prefix in-block)
  k_segsum<<<BATCH * SEG, 256, 0, stream>>>(KVh, segsum);
  k_retrieve_ln<<<BATCH * SEG, 256, 0, stream>>>(KVh, segsum, ln_g, ln_b, nb);

  // output GEMM with fp16 residual, 128x128 tiles, 2 blocks/CU
  k_gemm_out<<<(MROW / 128) * (DIMN / 128), 256, 65536, stream>>>(
      nb, wob, bo, xb, out);
}